// Round 16
// baseline (101.881 us; speedup 1.0000x reference)
//
#include <hip/hip_runtime.h>

#define N_NODES 8192
#define E_RAW   65536
#define NSLOT   (2*E_RAW + N_NODES)   // 139264 slots: [support E][flipped E][self-loops N]
#define DEGCAP  48                    // max deg ~36 (binomial, 8-sigma safe)
#define L_ITER  8
#define MAIN_BLKS (E_RAW / (4 * L_ITER))     // 2048 (2 waves x 2 edges x L_ITER)
#define TAIL_BLKS (N_NODES / (4 * L_ITER))   // 256

typedef __attribute__((ext_vector_type(8)))  short bf16x8;
typedef __attribute__((ext_vector_type(4)))  short bf16x4;
typedef __attribute__((ext_vector_type(4)))  float f32x4;
typedef __attribute__((ext_vector_type(16))) float f32x16;
typedef unsigned short u16;

__device__ __forceinline__ u16 f2b(float f) {
  unsigned u = __float_as_uint(f);
  u = (u + 0x7FFFu + ((u >> 16) & 1u)) >> 16;   // RNE
  return (u16)u;
}
__device__ __forceinline__ float b2f(u16 b) {
  return __uint_as_float(((unsigned)b) << 16);
}

// swizzled LDS read: physical row p (512B each), head h, element offset off
__device__ __forceinline__ bf16x4 kq_rd(const char* wbase, int p, int h, int off) {
  int byte = (p*512 + h*64 + off*2) ^ ((p & 7) << 4);
  return *(const bf16x4*)(wbase + byte);
}

// ---------------------------------------------------------------------------
// setup_k: cvtx (0..2047) + prep (2048..2835) + beW (2836) + zero (2837..2845)
__global__ __launch_bounds__(256) void setup_k(
    const float* __restrict__ x, u16* __restrict__ xb,
    const float* __restrict__ W_kqv, const float* __restrict__ b_kqv,
    const float* __restrict__ W_att1, const float* __restrict__ b_att1,
    const float* __restrict__ W_edge, const float* __restrict__ b_edge,
    const float* __restrict__ W_out,
    u16* __restrict__ BcatT, float* __restrict__ biascat,
    u16* __restrict__ wa1t, u16* __restrict__ WoutT, float* __restrict__ beW,
    int4* __restrict__ zbase)
{
  __shared__ float tile[64][65];
  const float inv_sqrt_hd = 0.17677669529663687f;  // 1/sqrt(32)
  int bx = blockIdx.x, t = threadIdx.x;

  if (bx < 2048) {                    // ---- cvtx
    int i = bx * 256 + t;
    float4 v = ((const float4*)x)[i];
    ushort4 o;
    o.x = f2b(v.x); o.y = f2b(v.y); o.z = f2b(v.z); o.w = f2b(v.w);
    ((ushort4*)xb)[i] = o;
    return;
  }
  if (bx < 2836) {                    // ---- prep
    int c = bx - 2048;
    int i = t;
    if (c < 768) {
      float v;
      if (c < 256) {
        int h = c >> 5, d2 = c & 31;
        float s = 0.f;
        #pragma unroll
        for (int j = 0; j < 32; ++j)
          s += W_kqv[i*768 + 256 + h*32 + j] * W_att1[j*32 + d2];
        v = s * inv_sqrt_hd;
      } else if (c < 512) {
        int c2 = c - 256; int h = c2 >> 5, d2 = c2 & 31;
        float s = 0.f;
        #pragma unroll
        for (int j = 0; j < 32; ++j)
          s += W_kqv[i*768 + h*32 + j] * W_att1[(32+j)*32 + d2];
        v = s;
      } else {
        v = W_kqv[i*768 + c];
      }
      BcatT[(size_t)c * 256 + i] = f2b(v);
      if (i == 0) {
        float bv;
        if (c < 256) {
          int h = c >> 5, d2 = c & 31;
          float s = 0.f;
          for (int j = 0; j < 32; ++j)
            s += b_kqv[256 + h*32 + j] * W_att1[j*32 + d2];
          bv = s * inv_sqrt_hd;
        } else if (c < 512) {
          int c2 = c - 256; int h = c2 >> 5, d2 = c2 & 31;
          float s = 0.f;
          for (int j = 0; j < 32; ++j)
            s += b_kqv[h*32 + j] * W_att1[(32+j)*32 + d2];
          bv = s + b_att1[c2 & 31];             // fold b_att1 into qW bias
        } else {
          bv = b_kqv[c];
        }
        biascat[c] = bv;
      }
    } else if (c < 772) {
      int idx = (c - 768) * 256 + i;
      int d2 = idx >> 5, j = idx & 31;
      wa1t[idx] = f2b(W_att1[(64 + j) * 32 + d2]);
    } else {
      int b = c - 772;
      int r0 = (b >> 2) * 64, c0 = (b & 3) * 64;
      for (int idx = i; idx < 4096; idx += 256) {
        int r = idx >> 6, cc = idx & 63;
        tile[r][cc] = W_out[(size_t)(r0 + r) * 256 + c0 + cc];
      }
      __syncthreads();
      for (int idx = i; idx < 4096; idx += 256) {
        int cc = idx >> 6, r = idx & 63;
        WoutT[(size_t)(c0 + cc) * 256 + r0 + r] = f2b(tile[r][cc]);
      }
    }
    return;
  }
  if (bx == 2836) {                   // ---- beW[h][d2] = relu(b_edge[h,:]) @ W1b
    int h = t >> 5, d2 = t & 31;
    float s = 0.f;
    #pragma unroll
    for (int f = 0; f < 32; ++f)
      s += fmaxf(b_edge[h*32 + f], 0.f) * W_att1[(64 + f)*32 + d2];
    beW[h*32 + d2] = s;
    return;
  }
  // ---- zero cnt+bnsum+bnsq (2176 int4 = 8704 ints, contiguous)
  int i = (bx - 2837) * 256 + t;
  if (i < 2176) zbase[i] = make_int4(0, 0, 0, 0);
}

// ---------------------------------------------------------------------------
// Fused: nodeF GEMM (blocks 0..767) + CSR scatter (blocks 768..1311).
__global__ __launch_bounds__(256) void gemm_scatter_k(
    const u16* __restrict__ xb, const u16* __restrict__ BcatT,
    const float* __restrict__ biascat, u16* __restrict__ nodeF,
    const int* __restrict__ ei, const int* __restrict__ qm,
    int* __restrict__ cnt, int* __restrict__ csr)
{
  int bx = blockIdx.x, t = threadIdx.x;
  if (bx < 768) {
    int lane = t & 63, wid = t >> 6;
    int cb = bx % 12, rb = bx / 12;           // col-tile fastest: A-panel L2 reuse
    int r0 = rb * 128 + wid * 32;
    int c0 = cb * 64;
    int lr = lane & 15, lk = (lane >> 4) * 8;
    f32x4 acc0[4] = {}, acc1[4] = {};
    for (int k0 = 0; k0 < 256; k0 += 32) {
      bf16x8 a0 = *(const bf16x8*)&xb[(size_t)(r0 + lr) * 256 + k0 + lk];
      bf16x8 a1 = *(const bf16x8*)&xb[(size_t)(r0 + 16 + lr) * 256 + k0 + lk];
      bf16x8 b0 = *(const bf16x8*)&BcatT[(size_t)(c0 + lr) * 256 + k0 + lk];
      bf16x8 b1 = *(const bf16x8*)&BcatT[(size_t)(c0 + 16 + lr) * 256 + k0 + lk];
      bf16x8 b2 = *(const bf16x8*)&BcatT[(size_t)(c0 + 32 + lr) * 256 + k0 + lk];
      bf16x8 b3 = *(const bf16x8*)&BcatT[(size_t)(c0 + 48 + lr) * 256 + k0 + lk];
      acc0[0] = __builtin_amdgcn_mfma_f32_16x16x32_bf16(a0, b0, acc0[0], 0, 0, 0);
      acc0[1] = __builtin_amdgcn_mfma_f32_16x16x32_bf16(a0, b1, acc0[1], 0, 0, 0);
      acc0[2] = __builtin_amdgcn_mfma_f32_16x16x32_bf16(a0, b2, acc0[2], 0, 0, 0);
      acc0[3] = __builtin_amdgcn_mfma_f32_16x16x32_bf16(a0, b3, acc0[3], 0, 0, 0);
      acc1[0] = __builtin_amdgcn_mfma_f32_16x16x32_bf16(a1, b0, acc1[0], 0, 0, 0);
      acc1[1] = __builtin_amdgcn_mfma_f32_16x16x32_bf16(a1, b1, acc1[1], 0, 0, 0);
      acc1[2] = __builtin_amdgcn_mfma_f32_16x16x32_bf16(a1, b2, acc1[2], 0, 0, 0);
      acc1[3] = __builtin_amdgcn_mfma_f32_16x16x32_bf16(a1, b3, acc1[3], 0, 0, 0);
    }
    int rbase = r0 + (lane >> 4) * 4;
    #pragma unroll
    for (int cc = 0; cc < 4; ++cc) {
      float bias = biascat[c0 + cc*16 + lr];
      #pragma unroll
      for (int r = 0; r < 4; ++r) {
        nodeF[(size_t)(rbase + r) * 768 + c0 + cc*16 + lr]      = f2b(acc0[cc][r] + bias);
        nodeF[(size_t)(rbase + 16 + r) * 768 + c0 + cc*16 + lr] = f2b(acc1[cc][r] + bias);
      }
    }
    return;
  }
  // ---- scatter: packed CSR (slot<<13 | src)
  int slot = (bx - 768) * 256 + t;
  if (slot >= NSLOT) return;
  int src, dst;
  if (slot < E_RAW) {
    if (qm[slot] != 0) return;
    src = ei[slot]; dst = ei[E_RAW + slot];
  } else if (slot < 2*E_RAW) {
    int e = slot - E_RAW;
    src = ei[E_RAW + e]; dst = ei[e];
  } else {
    int n = slot - 2*E_RAW;
    src = n; dst = n;
  }
  int pos = atomicAdd(&cnt[dst], 1);
  if (pos < DEGCAP) csr[dst*DEGCAP + pos] = (slot << 13) | src;
}

// ---------------------------------------------------------------------------
// logits, DMA depth-1 pipeline, 2 edges/wave-iter (16KB LDS -> 20 waves/CU).
// Masked edges fetch only needed halves (duplicate addr -> L2 hit).
__global__ __launch_bounds__(128) void logits_k(
    const int* __restrict__ ei, const int* __restrict__ qm,
    const float* __restrict__ eattr, const u16* __restrict__ nf,
    const u16* __restrict__ wa1t,
    const float* __restrict__ W_edge, const float* __restrict__ b_edge,
    const float* __restrict__ W_att2, const float* __restrict__ beW,
    float* __restrict__ lgd)
{
  __shared__ __align__(16) char kq_raw[2][2][4096];   // [wave][buf] 16 KB

  int bx = blockIdx.x, t = threadIdx.x, lane = t & 63, wid = t >> 6;
  int col = lane & 31;
  int e = col >> 3, h = col & 7, hi = lane >> 5;
  int je = e & 1;                                      // effective edge (0/1)

  float w2r[16];
  #pragma unroll
  for (int r = 0; r < 16; ++r)
    w2r[r] = W_att2[(r & 3) + 8*(r >> 2) + 4*hi];

  if (bx < MAIN_BLKS) {
    float ce0[16], ce1[16], cbe[16];
    #pragma unroll
    for (int i = 0; i < 8; ++i) {
      int fA = hi*8 + i, fB = 16 + hi*8 + i;
      ce0[i]   = W_edge[h*32 + fA];       ce0[8+i] = W_edge[h*32 + fB];
      ce1[i]   = W_edge[256 + h*32 + fA]; ce1[8+i] = W_edge[256 + h*32 + fB];
      cbe[i]   = b_edge[h*32 + fA];       cbe[8+i] = b_edge[h*32 + fB];
    }
    bf16x8 af0 = *(const bf16x8*)&wa1t[(lane & 31)*32 + hi*8];
    bf16x8 af1 = *(const bf16x8*)&wa1t[(lane & 31)*32 + 16 + hi*8];

    // preload all iteration scalars (ns/nd/qm: uniform -> SGPR)
    float2 ea_r[L_ITER];
    int2 nsv[L_ITER], ndv[L_ITER], qmv[L_ITER];
    #pragma unroll
    for (int it = 0; it < L_ITER; ++it) {
      int er0 = ((bx * L_ITER + it) * 2 + wid) * 2;
      ea_r[it] = *(const float2*)&eattr[2*(er0 + je)];
      nsv[it] = *(const int2*)&ei[er0];
      ndv[it] = *(const int2*)&ei[E_RAW + er0];
      qmv[it] = *(const int2*)&qm[er0];
    }

    unsigned lbase = (unsigned)((lane & 31) * 16);
    __builtin_amdgcn_sched_barrier(0);
    // prologue DMA(0) -> buf0: m = type(m>>1: 0=src,1=dst) x edge(m&1)
    {
      char* base = kq_raw[wid][0];
      #pragma unroll
      for (int m = 0; m < 4; ++m) {
        int ed = m & 1, ty = m >> 1;
        int node = ty ? ((&ndv[0].x)[ed]) : ((&nsv[0].x)[ed]);
        int msk = ((&qmv[0].x)[ed]) != 0;
        int halfsel = ty ? (msk ? 0 : hi) : (msk ? 1 : hi);
        int p = 2*m + hi;
        unsigned goff = lbase ^ (unsigned)((p & 7) << 4);
        const char* src = (const char*)nf + (size_t)node*1536
                        + (size_t)halfsel*512 + goff;
        __builtin_amdgcn_global_load_lds(
            (const __attribute__((address_space(1))) void*)src,
            (__attribute__((address_space(3))) void*)(base + m*1024), 16, 0, 0);
      }
    }
    __builtin_amdgcn_sched_barrier(0);

    #pragma unroll
    for (int it = 0; it < L_ITER; ++it) {
      // issue DMA(it+1) into the other buffer
      if (it + 1 < L_ITER) {
        char* base = kq_raw[wid][(it + 1) & 1];
        #pragma unroll
        for (int m = 0; m < 4; ++m) {
          int ed = m & 1, ty = m >> 1;
          int node = ty ? ((&ndv[it+1].x)[ed]) : ((&nsv[it+1].x)[ed]);
          int msk = ((&qmv[it+1].x)[ed]) != 0;
          int halfsel = ty ? (msk ? 0 : hi) : (msk ? 1 : hi);
          int p = 2*m + hi;
          unsigned goff = lbase ^ (unsigned)((p & 7) << 4);
          const char* src = (const char*)nf + (size_t)node*1536
                          + (size_t)halfsel*512 + goff;
          __builtin_amdgcn_global_load_lds(
              (const __attribute__((address_space(1))) void*)src,
              (__attribute__((address_space(3))) void*)(base + m*1024), 16, 0, 0);
        }
      }
      __builtin_amdgcn_sched_barrier(0);

      // COMP(it): edge-feature B-frags + MFMA (overlaps DMA latency)
      float2 ea = ea_r[it];
      bf16x8 bf0, bf1;
      #pragma unroll
      for (int i = 0; i < 8; ++i) {
        float v0 = fmaf(ea.x, ce0[i],   fmaf(ea.y, ce1[i],   cbe[i]));
        float v1 = fmaf(ea.x, ce0[8+i], fmaf(ea.y, ce1[8+i], cbe[8+i]));
        bf0[i] = (short)f2b(fmaxf(v0, 0.f));
        bf1[i] = (short)f2b(fmaxf(v1, 0.f));
      }
      f32x16 acc = {};
      acc = __builtin_amdgcn_mfma_f32_32x32x16_bf16(af0, bf0, acc, 0, 0, 0);
      acc = __builtin_amdgcn_mfma_f32_32x32x16_bf16(af1, bf1, acc, 0, 0, 0);

      __builtin_amdgcn_sched_barrier(0);
      // drain DMA(it): newer ops = DMA(it+1)[4] + store(it-1)[1 if it>0]
      if (it == 0)              asm volatile("s_waitcnt vmcnt(4)" ::: "memory");
      else if (it + 1 < L_ITER) asm volatile("s_waitcnt vmcnt(5)" ::: "memory");
      else                      asm volatile("s_waitcnt vmcnt(1)" ::: "memory");
      __builtin_amdgcn_sched_barrier(0);

      // EPI(it): reads buf[it&1]. phys rows: k_src(e)=2e, q_src=2e+1,
      // k_dst=4+2e, q_dst=5+2e.
      const char* wbase = kq_raw[wid][it & 1];
      float lg0 = 0.f, lg1 = 0.f;
      #pragma unroll
      for (int q = 0; q < 4; ++q) {
        int off = q*8 + 4*hi;
        bf16x4 k0 = kq_rd(wbase, 2*je,     h, off);
        bf16x4 q0 = kq_rd(wbase, 5 + 2*je, h, off);
        bf16x4 k1 = kq_rd(wbase, 4 + 2*je, h, off);
        bf16x4 q1 = kq_rd(wbase, 2*je + 1, h, off);
        #pragma unroll
        for (int j = 0; j < 4; ++j) {
          int r = q*4 + j;
          float efw = acc[r];
          float p0 = efw + b2f((u16)k0[j]) + b2f((u16)q0[j]);
          float p1 = efw + b2f((u16)k1[j]) + b2f((u16)q1[j]);
          lg0 = fmaf(fmaxf(p0, 0.f), w2r[r], lg0);
          lg1 = fmaf(fmaxf(p1, 0.f), w2r[r], lg1);
        }
      }
      lg0 += __shfl_xor(lg0, 32);
      lg1 += __shfl_xor(lg1, 32);
      // ONE vmem store instruction (lanes e>=2 masked; masked-support slots
      // hold garbage that the CSR never references)
      int er = ((bx * L_ITER + it) * 2 + wid) * 2 + je;
      size_t soff = hi ? ((size_t)(E_RAW + er)*8 + h) : ((size_t)er*8 + h);
      float sval = hi ? lg1 : lg0;
      if (e < 2) lgd[soff] = sval;
      __builtin_amdgcn_sched_barrier(0);
    }
  } else {
    float bew[16];
    #pragma unroll
    for (int r = 0; r < 16; ++r)
      bew[r] = beW[h*32 + (r & 3) + 8*(r >> 2) + 4*hi];

    unsigned lbase = (unsigned)((lane & 31) * 16);
    char* base = kq_raw[wid][0];
    for (int it = 0; it < L_ITER; ++it) {
      int n0 = (((bx - MAIN_BLKS) * L_ITER + it) * 2 + wid) * 2;
      #pragma unroll
      for (int m = 0; m < 2; ++m) {
        int p = 2*m + hi;
        unsigned goff = lbase ^ (unsigned)((p & 7) << 4);
        const char* src = (const char*)nf + (size_t)(n0 + m)*1536
                        + (size_t)hi*512 + goff;
        __builtin_amdgcn_global_load_lds(
            (const __attribute__((address_space(1))) void*)src,
            (__attribute__((address_space(3))) void*)(base + m*1024), 16, 0, 0);
      }
      asm volatile("s_waitcnt vmcnt(0)" ::: "memory");
      __builtin_amdgcn_sched_barrier(0);
      float lg0 = 0.f;
      #pragma unroll
      for (int q = 0; q < 4; ++q) {
        int off = q*8 + 4*hi;
        bf16x4 k0 = kq_rd(base, 2*je,     h, off);
        bf16x4 q0 = kq_rd(base, 2*je + 1, h, off);
        #pragma unroll
        for (int j = 0; j < 4; ++j) {
          int r = q*4 + j;
          float p = bew[r] + b2f((u16)k0[j]) + b2f((u16)q0[j]);
          lg0 = fmaf(fmaxf(p, 0.f), w2r[r], lg0);
        }
      }
      lg0 += __shfl_xor(lg0, 32);
      if (hi == 0 && e < 2) lgd[(size_t)(2*E_RAW + n0 + je)*8 + h] = lg0;
      __builtin_amdgcn_sched_barrier(0);
    }
  }
}

// ---------------------------------------------------------------------------
// Per-node ONLINE segment softmax + alpha-weighted V aggregation, single pass.
__global__ __launch_bounds__(256) void aggr_k(const int* __restrict__ cnt,
                                              const int* __restrict__ csr,
                                              const float* __restrict__ lgd,
                                              const u16* __restrict__ nf,
                                              u16* __restrict__ aggb) {
  int t = threadIdx.x, lane = t & 63, wid = t >> 6;
  int n = blockIdx.x * 4 + wid;
  int deg = cnt[n]; if (deg > DEGCAP) deg = DEGCAP;
  int head = lane >> 3;

  int pk = (lane < deg) ? csr[n*DEGCAP + lane] : 0;

  const u16* vb = nf + 512 + lane * 4;
  int pk0 = __shfl(pk, 0);                      // deg >= 1 (self-loop)
  float lg_pf = lgd[(size_t)((unsigned)pk0 >> 13)*8 + head];
  bf16x4 v_pf = *(const bf16x4*)&vb[(size_t)(pk0 & 8191) * 768];

  float m = -3.4e38f, s = 0.f;
  float ac0 = 0.f, ac1 = 0.f, ac2 = 0.f, ac3 = 0.f;
  for (int i = 0; i < deg; ++i) {
    float lgv = lg_pf;
    bf16x4 v = v_pf;
    if (i + 1 < deg) {
      int pkn = __shfl(pk, i + 1);
      lg_pf = lgd[(size_t)((unsigned)pkn >> 13)*8 + head];
      v_pf = *(const bf16x4*)&vb[(size_t)(pkn & 8191) * 768];
    }
    float mn = fmaxf(m, lgv);
    float r = __expf(m - mn);
    float a = __expf(lgv - mn);
    s  = fmaf(s, r, a);
    ac0 = fmaf(ac0, r, a * b2f((u16)v[0]));
    ac1 = fmaf(ac1, r, a * b2f((u16)v[1]));
    ac2 = fmaf(ac2, r, a * b2f((u16)v[2]));
    ac3 = fmaf(ac3, r, a * b2f((u16)v[3]));
    m = mn;
  }
  float sinv = 1.f / (s + 1e-16f);
  ushort4 o;
  o.x = f2b(ac0 * sinv); o.y = f2b(ac1 * sinv);
  o.z = f2b(ac2 * sinv); o.w = f2b(ac3 * sinv);
  *(ushort4*)&aggb[(size_t)n * 256 + lane * 4] = o;
}

// ---------------------------------------------------------------------------
// out = aggb @ WoutT^T + x + deg*b_out (fp32 out), fused BN partial sums.
__global__ __launch_bounds__(256) void gemmout_k(const u16* __restrict__ aggb,
                                                 const u16* __restrict__ WoutT,
                                                 const float* __restrict__ x,
                                                 const int* __restrict__ cnt,
                                                 const float* __restrict__ b_out,
                                                 float* __restrict__ out,
                                                 float* __restrict__ bnsum,
                                                 float* __restrict__ bnsq) {
  int t = threadIdx.x, lane = t & 63, wid = t >> 6;
  int bx = blockIdx.x;
  int cb = bx & 3, rb = bx >> 2;
  int r0 = rb * 128 + wid * 32;
  int c0 = cb * 64;
  int lr = lane & 15, lk = (lane >> 4) * 8;
  f32x4 acc0[4] = {}, acc1[4] = {};
  for (int k0 = 0; k0 < 256; k0 += 32) {
    bf16x8 a0 = *(const bf16x8*)&aggb[(size_t)(r0 + lr) * 256 + k0 + lk];
    bf16x8 a1 = *(const bf16x8*)&aggb[(size_t)(r0 + 16 + lr) * 256 + k0 + lk];
    bf16x8 b0 = *(const bf16x8*)&WoutT[(size_t)(c0 + lr) * 256 + k0 + lk];
    bf16x8 b1 = *(const bf16x8*)&WoutT[(size_t)(c0 + 16 + lr) * 256 + k0 + lk];
    bf16x8 b2 = *(const bf16x8*)&WoutT[(size_t)(c0 + 32 + lr) * 256 + k0 + lk];
    bf16x8 b3 = *(const bf16x8*)&WoutT[(size_t)(c0 + 48 + lr) * 256 + k0 + lk];
    acc0[0] = __builtin_amdgcn_mfma_f32_16x16x32_bf16(a0, b0, acc0[0], 0, 0, 0);
    acc0[1] = __builtin_amdgcn_mfma_f32_16x16x32_bf16(a0, b1, acc0[1], 0, 0, 0);
    acc0[2] = __builtin_amdgcn_mfma_f32_16x16x32_bf16(a0, b2, acc0[2], 0, 0, 0);
    acc0[3] = __builtin_amdgcn_mfma_f32_16x16x32_bf16(a0, b3, acc0[3], 0, 0, 0);
    acc1[0] = __builtin_amdgcn_mfma_f32_16x16x32_bf16(a1, b0, acc1[0], 0, 0, 0);
    acc1[1] = __builtin_amdgcn_mfma_f32_16x16x32_bf16(a1, b1, acc1[1], 0, 0, 0);
    acc1[2] = __builtin_amdgcn_mfma_f32_16x16x32_bf16(a1, b2, acc1[2], 0, 0, 0);
    acc1[3] = __builtin_amdgcn_mfma_f32_16x16x32_bf16(a1, b3, acc1[3], 0, 0, 0);
  }
  int rbase = r0 + (lane >> 4) * 4;
  float degA[4], degB[4];
  #pragma unroll
  for (int r = 0; r < 4; ++r) {
    degA[r] = (float)cnt[rbase + r];
    degB[r] = (float)cnt[rbase + 16 + r];
  }
  #pragma unroll
  for (int cc = 0; cc < 4; ++cc) {
    int colC = c0 + cc*16 + lr;
    float bC = b_out[colC];
    float sC = 0.f, qC = 0.f;
    #pragma unroll
    for (int r = 0; r < 4; ++r) {
      int rowA = rbase + r, rowB = rbase + 16 + r;
      float v0 = acc0[cc][r] + x[(size_t)rowA * 256 + colC] + degA[r] * bC;
      float v1 = acc1[cc][r] + x[(size_t)rowB * 256 + colC] + degB[r] * bC;
      out[(size_t)rowA * 256 + colC] = v0;
      out[(size_t)rowB * 256 + colC] = v1;
      sC += v0 + v1; qC += v0*v0 + v1*v1;
    }
    #pragma unroll
    for (int msk = 16; msk <= 32; msk <<= 1) {
      sC += __shfl_xor(sC, msk); qC += __shfl_xor(qC, msk);
    }
    if (lane < 16) {
      atomicAdd(&bnsum[colC], sC); atomicAdd(&bnsq[colC], qC);
    }
  }
}

// ---------------------------------------------------------------------------
__global__ __launch_bounds__(256) void bnapply_k(float* __restrict__ out,
                                                 const float* __restrict__ bnsum,
                                                 const float* __restrict__ bnsq,
                                                 const float* __restrict__ gamma,
                                                 const float* __restrict__ beta) {
  int t = threadIdx.x;
  int c4 = t & 63;
  int r = blockIdx.x * 4 + (t >> 6);
  float4 s4 = ((const float4*)bnsum)[c4];
  float4 q4 = ((const float4*)bnsq)[c4];
  float4 g4 = ((const float4*)gamma)[c4];
  float4 b4 = ((const float4*)beta)[c4];
  float4 v = ((const float4*)out)[(size_t)r * 64 + c4];
  #pragma unroll
  for (int j = 0; j < 4; ++j) {
    float mu = (&s4.x)[j] * (1.f / 8192.f);
    float var = (&q4.x)[j] * (1.f / 8192.f) - mu*mu;
    float inv = rsqrtf(var + 1e-5f);
    (&v.x)[j] = ((&v.x)[j] - mu) * inv * (&g4.x)[j] + (&b4.x)[j];
  }
  ((float4*)out)[(size_t)r * 64 + c4] = v;
}

// ---------------------------------------------------------------------------
extern "C" void kernel_launch(void* const* d_in, const int* in_sizes, int n_in,
                              void* d_out, int out_size, void* d_ws, size_t ws_size,
                              hipStream_t stream) {
  (void)in_sizes; (void)n_in; (void)out_size; (void)ws_size;
  const float* x      = (const float*)d_in[0];
  const int*   ei     = (const int*)d_in[1];
  const float* eattr  = (const float*)d_in[2];
  const int*   qm     = (const int*)d_in[3];
  const float* W_kqv  = (const float*)d_in[5];
  const float* b_kqv  = (const float*)d_in[6];
  const float* W_edge = (const float*)d_in[7];
  const float* b_edge = (const float*)d_in[8];
  const float* W_att1 = (const float*)d_in[9];
  const float* b_att1 = (const float*)d_in[10];
  const float* W_att2 = (const float*)d_in[11];
  // b_att2 cancels in softmax
  const float* W_out  = (const float*)d_in[13];
  const float* b_out  = (const float*)d_in[14];
  const float* gamma  = (const float*)d_in[15];
  const float* beta   = (const float*)d_in[16];
  float* out = (float*)d_out;

  // workspace carve-up (~27 MB)
  char* w = (char*)d_ws;
  u16*    xb      = (u16*)w;     w += (size_t)N_NODES*256*2;
  u16*    BcatT   = (u16*)w;     w += (size_t)768*256*2;
  u16*    wa1t    = (u16*)w;     w += 1024*2;
  u16*    WoutT   = (u16*)w;     w += (size_t)256*256*2;
  u16*    nodeFb  = (u16*)w;     w += (size_t)N_NODES*768*2;
  float*  biascat = (float*)w;   w += 768*4;
  float*  beW     = (float*)w;   w += 256*4;
  u16*    aggb    = (u16*)w;     w += (size_t)N_NODES*256*2;
  int*    cnt     = (int*)w;     w += N_NODES*4;
  float*  bnsum   = (float*)w;   w += 256*4;
  float*  bnsq    = (float*)w;   w += 256*4;
  int*    csr     = (int*)w;     w += (size_t)N_NODES*DEGCAP*4;
  float*  lgd     = (float*)w;   w += (size_t)NSLOT*8*4;

  setup_k<<<2846, 256, 0, stream>>>(
      x, xb, W_kqv, b_kqv, W_att1, b_att1, W_edge, b_edge, W_out,
      BcatT, biascat, wa1t, WoutT, beW, (int4*)cnt);

  gemm_scatter_k<<<768 + (NSLOT + 255)/256, 256, 0, stream>>>(
      xb, BcatT, biascat, nodeFb, ei, qm, cnt, csr);

  logits_k<<<MAIN_BLKS + TAIL_BLKS, 128, 0, stream>>>(
      ei, qm, eattr, nodeFb, wa1t, W_edge, b_edge, W_att2, beW, lgd);

  aggr_k<<<N_NODES/4, 256, 0, stream>>>(cnt, csr, lgd, nodeFb, aggb);

  gemmout_k<<<256, 256, 0, stream>>>(
      aggb, WoutT, x, cnt, b_out, out, bnsum, bnsq);

  bnapply_k<<<N_NODES/4, 256, 0, stream>>>(out, bnsum, bnsq, gamma, beta);
}

// Round 17
// 94.920 us; speedup vs baseline: 1.0733x; 1.0733x over previous
//
#include <hip/hip_runtime.h>

#define N_NODES 8192
#define E_RAW   65536
#define NSLOT   (2*E_RAW + N_NODES)   // 139264 slots: [support E][flipped E][self-loops N]
#define DEGCAP  48                    // max deg ~36 (binomial, 8-sigma safe)
#define L_ITER  4
#define MAIN_BLKS (E_RAW / (8 * L_ITER))     // 2048 (2 waves x 4 edges x L_ITER)
#define TAIL_BLKS (N_NODES / (8 * L_ITER))   // 256

typedef __attribute__((ext_vector_type(8)))  short bf16x8;
typedef __attribute__((ext_vector_type(4)))  short bf16x4;
typedef __attribute__((ext_vector_type(4)))  float f32x4;
typedef __attribute__((ext_vector_type(16))) float f32x16;
typedef unsigned short u16;

__device__ __forceinline__ u16 f2b(float f) {
  unsigned u = __float_as_uint(f);
  u = (u + 0x7FFFu + ((u >> 16) & 1u)) >> 16;   // RNE
  return (u16)u;
}
__device__ __forceinline__ float b2f(u16 b) {
  return __uint_as_float(((unsigned)b) << 16);
}

// swizzled LDS read: physical row p (512B each), head h, element offset off
__device__ __forceinline__ bf16x4 kq_rd(const char* wbase, int p, int h, int off) {
  int byte = (p*512 + h*64 + off*2) ^ ((p & 7) << 4);
  return *(const bf16x4*)(wbase + byte);
}

// ---------------------------------------------------------------------------
// setup_k: cvtx (0..2047) + prep (2048..2835) + beW (2836) + zero (2837..2845)
__global__ __launch_bounds__(256) void setup_k(
    const float* __restrict__ x, u16* __restrict__ xb,
    const float* __restrict__ W_kqv, const float* __restrict__ b_kqv,
    const float* __restrict__ W_att1, const float* __restrict__ b_att1,
    const float* __restrict__ W_edge, const float* __restrict__ b_edge,
    const float* __restrict__ W_out,
    u16* __restrict__ BcatT, float* __restrict__ biascat,
    u16* __restrict__ wa1t, u16* __restrict__ WoutT, float* __restrict__ beW,
    int4* __restrict__ zbase)
{
  __shared__ float tile[64][65];
  const float inv_sqrt_hd = 0.17677669529663687f;  // 1/sqrt(32)
  int bx = blockIdx.x, t = threadIdx.x;

  if (bx < 2048) {                    // ---- cvtx
    int i = bx * 256 + t;
    float4 v = ((const float4*)x)[i];
    ushort4 o;
    o.x = f2b(v.x); o.y = f2b(v.y); o.z = f2b(v.z); o.w = f2b(v.w);
    ((ushort4*)xb)[i] = o;
    return;
  }
  if (bx < 2836) {                    // ---- prep
    int c = bx - 2048;
    int i = t;
    if (c < 768) {
      float v;
      if (c < 256) {
        int h = c >> 5, d2 = c & 31;
        float s = 0.f;
        #pragma unroll
        for (int j = 0; j < 32; ++j)
          s += W_kqv[i*768 + 256 + h*32 + j] * W_att1[j*32 + d2];
        v = s * inv_sqrt_hd;
      } else if (c < 512) {
        int c2 = c - 256; int h = c2 >> 5, d2 = c2 & 31;
        float s = 0.f;
        #pragma unroll
        for (int j = 0; j < 32; ++j)
          s += W_kqv[i*768 + h*32 + j] * W_att1[(32+j)*32 + d2];
        v = s;
      } else {
        v = W_kqv[i*768 + c];
      }
      BcatT[(size_t)c * 256 + i] = f2b(v);
      if (i == 0) {
        float bv;
        if (c < 256) {
          int h = c >> 5, d2 = c & 31;
          float s = 0.f;
          for (int j = 0; j < 32; ++j)
            s += b_kqv[256 + h*32 + j] * W_att1[j*32 + d2];
          bv = s * inv_sqrt_hd;
        } else if (c < 512) {
          int c2 = c - 256; int h = c2 >> 5, d2 = c2 & 31;
          float s = 0.f;
          for (int j = 0; j < 32; ++j)
            s += b_kqv[h*32 + j] * W_att1[(32+j)*32 + d2];
          bv = s + b_att1[c2 & 31];             // fold b_att1 into qW bias
        } else {
          bv = b_kqv[c];
        }
        biascat[c] = bv;
      }
    } else if (c < 772) {
      int idx = (c - 768) * 256 + i;
      int d2 = idx >> 5, j = idx & 31;
      wa1t[idx] = f2b(W_att1[(64 + j) * 32 + d2]);
    } else {
      int b = c - 772;
      int r0 = (b >> 2) * 64, c0 = (b & 3) * 64;
      for (int idx = i; idx < 4096; idx += 256) {
        int r = idx >> 6, cc = idx & 63;
        tile[r][cc] = W_out[(size_t)(r0 + r) * 256 + c0 + cc];
      }
      __syncthreads();
      for (int idx = i; idx < 4096; idx += 256) {
        int cc = idx >> 6, r = idx & 63;
        WoutT[(size_t)(c0 + cc) * 256 + r0 + r] = f2b(tile[r][cc]);
      }
    }
    return;
  }
  if (bx == 2836) {                   // ---- beW[h][d2] = relu(b_edge[h,:]) @ W1b
    int h = t >> 5, d2 = t & 31;
    float s = 0.f;
    #pragma unroll
    for (int f = 0; f < 32; ++f)
      s += fmaxf(b_edge[h*32 + f], 0.f) * W_att1[(64 + f)*32 + d2];
    beW[h*32 + d2] = s;
    return;
  }
  // ---- zero cnt+bnsum+bnsq (2176 int4 = 8704 ints, contiguous)
  int i = (bx - 2837) * 256 + t;
  if (i < 2176) zbase[i] = make_int4(0, 0, 0, 0);
}

// ---------------------------------------------------------------------------
// Fused: nodeF GEMM (blocks 0..767) + CSR scatter (blocks 768..1311).
__global__ __launch_bounds__(256) void gemm_scatter_k(
    const u16* __restrict__ xb, const u16* __restrict__ BcatT,
    const float* __restrict__ biascat, u16* __restrict__ nodeF,
    const int* __restrict__ ei, const int* __restrict__ qm,
    int* __restrict__ cnt, int* __restrict__ csr)
{
  int bx = blockIdx.x, t = threadIdx.x;
  if (bx < 768) {
    int lane = t & 63, wid = t >> 6;
    int cb = bx % 12, rb = bx / 12;           // col-tile fastest: A-panel L2 reuse
    int r0 = rb * 128 + wid * 32;
    int c0 = cb * 64;
    int lr = lane & 15, lk = (lane >> 4) * 8;
    f32x4 acc0[4] = {}, acc1[4] = {};
    for (int k0 = 0; k0 < 256; k0 += 32) {
      bf16x8 a0 = *(const bf16x8*)&xb[(size_t)(r0 + lr) * 256 + k0 + lk];
      bf16x8 a1 = *(const bf16x8*)&xb[(size_t)(r0 + 16 + lr) * 256 + k0 + lk];
      bf16x8 b0 = *(const bf16x8*)&BcatT[(size_t)(c0 + lr) * 256 + k0 + lk];
      bf16x8 b1 = *(const bf16x8*)&BcatT[(size_t)(c0 + 16 + lr) * 256 + k0 + lk];
      bf16x8 b2 = *(const bf16x8*)&BcatT[(size_t)(c0 + 32 + lr) * 256 + k0 + lk];
      bf16x8 b3 = *(const bf16x8*)&BcatT[(size_t)(c0 + 48 + lr) * 256 + k0 + lk];
      acc0[0] = __builtin_amdgcn_mfma_f32_16x16x32_bf16(a0, b0, acc0[0], 0, 0, 0);
      acc0[1] = __builtin_amdgcn_mfma_f32_16x16x32_bf16(a0, b1, acc0[1], 0, 0, 0);
      acc0[2] = __builtin_amdgcn_mfma_f32_16x16x32_bf16(a0, b2, acc0[2], 0, 0, 0);
      acc0[3] = __builtin_amdgcn_mfma_f32_16x16x32_bf16(a0, b3, acc0[3], 0, 0, 0);
      acc1[0] = __builtin_amdgcn_mfma_f32_16x16x32_bf16(a1, b0, acc1[0], 0, 0, 0);
      acc1[1] = __builtin_amdgcn_mfma_f32_16x16x32_bf16(a1, b1, acc1[1], 0, 0, 0);
      acc1[2] = __builtin_amdgcn_mfma_f32_16x16x32_bf16(a1, b2, acc1[2], 0, 0, 0);
      acc1[3] = __builtin_amdgcn_mfma_f32_16x16x32_bf16(a1, b3, acc1[3], 0, 0, 0);
    }
    int rbase = r0 + (lane >> 4) * 4;
    #pragma unroll
    for (int cc = 0; cc < 4; ++cc) {
      float bias = biascat[c0 + cc*16 + lr];
      #pragma unroll
      for (int r = 0; r < 4; ++r) {
        nodeF[(size_t)(rbase + r) * 768 + c0 + cc*16 + lr]      = f2b(acc0[cc][r] + bias);
        nodeF[(size_t)(rbase + 16 + r) * 768 + c0 + cc*16 + lr] = f2b(acc1[cc][r] + bias);
      }
    }
    return;
  }
  // ---- scatter: packed CSR (slot<<13 | src)
  int slot = (bx - 768) * 256 + t;
  if (slot >= NSLOT) return;
  int src, dst;
  if (slot < E_RAW) {
    if (qm[slot] != 0) return;
    src = ei[slot]; dst = ei[E_RAW + slot];
  } else if (slot < 2*E_RAW) {
    int e = slot - E_RAW;
    src = ei[E_RAW + e]; dst = ei[e];
  } else {
    int n = slot - 2*E_RAW;
    src = n; dst = n;
  }
  int pos = atomicAdd(&cnt[dst], 1);
  if (pos < DEGCAP) csr[dst*DEGCAP + pos] = (slot << 13) | src;
}

// ---------------------------------------------------------------------------
// logits, DMA + depth-1 double-buffer pipeline. 128 threads = 2 waves/block.
// Each wave: 4 edges/iter x L_ITER iters. All node indices preloaded (oldest
// vmem ops). Loop: issue DMA(it+1) -> EF/MFMA(it) -> counted vmcnt -> epilogue
// reads buf[it&1] -> ONE unconditional store (exact static vmem counts).
__global__ __launch_bounds__(128) void logits_k(
    const int* __restrict__ ei,
    const float* __restrict__ eattr, const u16* __restrict__ nf,
    const u16* __restrict__ wa1t,
    const float* __restrict__ W_edge, const float* __restrict__ b_edge,
    const float* __restrict__ W_att2, const float* __restrict__ beW,
    float* __restrict__ lgd)
{
  __shared__ __align__(16) char kq_raw[2][2][8192];   // [wave][buf] 32 KB

  int bx = blockIdx.x, t = threadIdx.x, lane = t & 63, wid = t >> 6;
  int col = lane & 31;
  int e = col >> 3, h = col & 7, hi = lane >> 5;

  float w2r[16];
  #pragma unroll
  for (int r = 0; r < 16; ++r)
    w2r[r] = W_att2[(r & 3) + 8*(r >> 2) + 4*hi];

  if (bx < MAIN_BLKS) {
    float ce0[16], ce1[16], cbe[16];
    #pragma unroll
    for (int i = 0; i < 8; ++i) {
      int fA = hi*8 + i, fB = 16 + hi*8 + i;
      ce0[i]   = W_edge[h*32 + fA];       ce0[8+i] = W_edge[h*32 + fB];
      ce1[i]   = W_edge[256 + h*32 + fA]; ce1[8+i] = W_edge[256 + h*32 + fB];
      cbe[i]   = b_edge[h*32 + fA];       cbe[8+i] = b_edge[h*32 + fB];
    }
    bf16x8 af0 = *(const bf16x8*)&wa1t[(lane & 31)*32 + hi*8];
    bf16x8 af1 = *(const bf16x8*)&wa1t[(lane & 31)*32 + 16 + hi*8];

    // per-iteration edge scalars + ALL node indices preloaded (oldest vmem)
    float2 ea_r[L_ITER];
    int4 nsv[L_ITER], ndv[L_ITER];
    #pragma unroll
    for (int it = 0; it < L_ITER; ++it) {
      int er0 = ((bx * L_ITER + it) * 2 + wid) * 4;
      ea_r[it] = *(const float2*)&eattr[2*(er0 + e)];
      nsv[it] = *(const int4*)&ei[er0];
      ndv[it] = *(const int4*)&ei[E_RAW + er0];
    }

    unsigned lbase = (unsigned)((lane & 31) * 16);
    __builtin_amdgcn_sched_barrier(0);
    // prologue DMA(0) -> buf0
    {
      char* base = kq_raw[wid][0];
      #pragma unroll
      for (int m = 0; m < 8; ++m) {
        int node = (m >> 2) ? ((&ndv[0].x)[m & 3]) : ((&nsv[0].x)[m & 3]);
        int p = 2*m + hi;
        unsigned goff = lbase ^ (unsigned)((p & 7) << 4);
        const char* src = (const char*)nf + (size_t)node*1536 + (size_t)hi*512 + goff;
        __builtin_amdgcn_global_load_lds(
            (const __attribute__((address_space(1))) void*)src,
            (__attribute__((address_space(3))) void*)(base + m*1024), 16, 0, 0);
      }
    }
    __builtin_amdgcn_sched_barrier(0);

    #pragma unroll
    for (int it = 0; it < L_ITER; ++it) {
      // issue DMA(it+1) into the other buffer
      if (it + 1 < L_ITER) {
        char* base = kq_raw[wid][(it + 1) & 1];
        #pragma unroll
        for (int m = 0; m < 8; ++m) {
          int node = (m >> 2) ? ((&ndv[it+1].x)[m & 3]) : ((&nsv[it+1].x)[m & 3]);
          int p = 2*m + hi;
          unsigned goff = lbase ^ (unsigned)((p & 7) << 4);
          const char* src = (const char*)nf + (size_t)node*1536 + (size_t)hi*512 + goff;
          __builtin_amdgcn_global_load_lds(
              (const __attribute__((address_space(1))) void*)src,
              (__attribute__((address_space(3))) void*)(base + m*1024), 16, 0, 0);
        }
      }
      __builtin_amdgcn_sched_barrier(0);

      // COMP(it): edge-feature B-frags + MFMA (overlaps DMA latency)
      float2 ea = ea_r[it];
      bf16x8 bf0, bf1;
      #pragma unroll
      for (int i = 0; i < 8; ++i) {
        float v0 = fmaf(ea.x, ce0[i],   fmaf(ea.y, ce1[i],   cbe[i]));
        float v1 = fmaf(ea.x, ce0[8+i], fmaf(ea.y, ce1[8+i], cbe[8+i]));
        bf0[i] = (short)f2b(fmaxf(v0, 0.f));
        bf1[i] = (short)f2b(fmaxf(v1, 0.f));
      }
      f32x16 acc = {};
      acc = __builtin_amdgcn_mfma_f32_32x32x16_bf16(af0, bf0, acc, 0, 0, 0);
      acc = __builtin_amdgcn_mfma_f32_32x32x16_bf16(af1, bf1, acc, 0, 0, 0);

      __builtin_amdgcn_sched_barrier(0);
      // drain DMA(it): exact newer-op count = DMA(it+1)[8] (+1 store, drained
      // harmlessly by 8); last iter: only store(it-1)[1] is newer.
      if (it + 1 < L_ITER) asm volatile("s_waitcnt vmcnt(8)" ::: "memory");
      else                 asm volatile("s_waitcnt vmcnt(1)" ::: "memory");
      __builtin_amdgcn_sched_barrier(0);

      // EPI(it): reads buf[it&1]
      const char* wbase = kq_raw[wid][it & 1];
      float lg0 = 0.f, lg1 = 0.f;
      #pragma unroll
      for (int q = 0; q < 4; ++q) {
        int off = q*8 + 4*hi;
        bf16x4 k0 = kq_rd(wbase, 2*e,     h, off);
        bf16x4 q0 = kq_rd(wbase, 2*e + 9, h, off);
        bf16x4 k1 = kq_rd(wbase, 2*e + 8, h, off);
        bf16x4 q1 = kq_rd(wbase, 2*e + 1, h, off);
        #pragma unroll
        for (int j = 0; j < 4; ++j) {
          int r = q*4 + j;
          float efw = acc[r];
          float p0 = efw + b2f((u16)k0[j]) + b2f((u16)q0[j]);
          float p1 = efw + b2f((u16)k1[j]) + b2f((u16)q1[j]);
          lg0 = fmaf(fmaxf(p0, 0.f), w2r[r], lg0);
          lg1 = fmaf(fmaxf(p1, 0.f), w2r[r], lg1);
        }
      }
      lg0 += __shfl_xor(lg0, 32);
      lg1 += __shfl_xor(lg1, 32);
      // ONE unconditional store per lane (masked support slots hold garbage
      // that the CSR never references)
      int er = ((bx * L_ITER + it) * 2 + wid) * 4 + e;
      size_t soff = hi ? ((size_t)(E_RAW + er)*8 + h) : ((size_t)er*8 + h);
      lgd[soff] = hi ? lg1 : lg0;
      __builtin_amdgcn_sched_barrier(0);
    }
  } else {
    float bew[16];
    #pragma unroll
    for (int r = 0; r < 16; ++r)
      bew[r] = beW[h*32 + (r & 3) + 8*(r >> 2) + 4*hi];

    unsigned lbase = (unsigned)((lane & 31) * 16);
    char* base = kq_raw[wid][0];
    for (int it = 0; it < L_ITER; ++it) {
      int n0 = (((bx - MAIN_BLKS) * L_ITER + it) * 2 + wid) * 4;
      int nn = n0 + e;
      #pragma unroll
      for (int m = 0; m < 4; ++m) {
        int p = 2*m + hi;
        unsigned goff = lbase ^ (unsigned)((p & 7) << 4);
        const char* src = (const char*)nf + (size_t)(n0 + m)*1536 + (size_t)hi*512 + goff;
        __builtin_amdgcn_global_load_lds(
            (const __attribute__((address_space(1))) void*)src,
            (__attribute__((address_space(3))) void*)(base + m*1024), 16, 0, 0);
      }
      asm volatile("s_waitcnt vmcnt(0)" ::: "memory");
      __builtin_amdgcn_sched_barrier(0);
      float lg0 = 0.f;
      #pragma unroll
      for (int q = 0; q < 4; ++q) {
        int off = q*8 + 4*hi;
        bf16x4 k0 = kq_rd(base, 2*e,     h, off);
        bf16x4 q0 = kq_rd(base, 2*e + 1, h, off);
        #pragma unroll
        for (int j = 0; j < 4; ++j) {
          int r = q*4 + j;
          float p = bew[r] + b2f((u16)k0[j]) + b2f((u16)q0[j]);
          lg0 = fmaf(fmaxf(p, 0.f), w2r[r], lg0);
        }
      }
      lg0 += __shfl_xor(lg0, 32);
      if (hi == 0) lgd[(size_t)(2*E_RAW + nn)*8 + h] = lg0;
      __builtin_amdgcn_sched_barrier(0);
    }
  }
}

// ---------------------------------------------------------------------------
// Per-node ONLINE segment softmax + alpha-weighted V aggregation, single pass.
__global__ __launch_bounds__(256) void aggr_k(const int* __restrict__ cnt,
                                              const int* __restrict__ csr,
                                              const float* __restrict__ lgd,
                                              const u16* __restrict__ nf,
                                              u16* __restrict__ aggb) {
  int t = threadIdx.x, lane = t & 63, wid = t >> 6;
  int n = blockIdx.x * 4 + wid;
  int deg = cnt[n]; if (deg > DEGCAP) deg = DEGCAP;
  int head = lane >> 3;

  int pk = (lane < deg) ? csr[n*DEGCAP + lane] : 0;

  const u16* vb = nf + 512 + lane * 4;
  int pk0 = __shfl(pk, 0);                      // deg >= 1 (self-loop)
  float lg_pf = lgd[(size_t)((unsigned)pk0 >> 13)*8 + head];
  bf16x4 v_pf = *(const bf16x4*)&vb[(size_t)(pk0 & 8191) * 768];

  float m = -3.4e38f, s = 0.f;
  float ac0 = 0.f, ac1 = 0.f, ac2 = 0.f, ac3 = 0.f;
  for (int i = 0; i < deg; ++i) {
    float lgv = lg_pf;
    bf16x4 v = v_pf;
    if (i + 1 < deg) {
      int pkn = __shfl(pk, i + 1);
      lg_pf = lgd[(size_t)((unsigned)pkn >> 13)*8 + head];
      v_pf = *(const bf16x4*)&vb[(size_t)(pkn & 8191) * 768];
    }
    float mn = fmaxf(m, lgv);
    float r = __expf(m - mn);
    float a = __expf(lgv - mn);
    s  = fmaf(s, r, a);
    ac0 = fmaf(ac0, r, a * b2f((u16)v[0]));
    ac1 = fmaf(ac1, r, a * b2f((u16)v[1]));
    ac2 = fmaf(ac2, r, a * b2f((u16)v[2]));
    ac3 = fmaf(ac3, r, a * b2f((u16)v[3]));
    m = mn;
  }
  float sinv = 1.f / (s + 1e-16f);
  ushort4 o;
  o.x = f2b(ac0 * sinv); o.y = f2b(ac1 * sinv);
  o.z = f2b(ac2 * sinv); o.w = f2b(ac3 * sinv);
  *(ushort4*)&aggb[(size_t)n * 256 + lane * 4] = o;
}

// ---------------------------------------------------------------------------
// out = aggb @ WoutT^T + x + deg*b_out (fp32 out), fused BN partial sums.
__global__ __launch_bounds__(256) void gemmout_k(const u16* __restrict__ aggb,
                                                 const u16* __restrict__ WoutT,
                                                 const float* __restrict__ x,
                                                 const int* __restrict__ cnt,
                                                 const float* __restrict__ b_out,
                                                 float* __restrict__ out,
                                                 float* __restrict__ bnsum,
                                                 float* __restrict__ bnsq) {
  int t = threadIdx.x, lane = t & 63, wid = t >> 6;
  int bx = blockIdx.x;
  int cb = bx & 3, rb = bx >> 2;
  int r0 = rb * 128 + wid * 32;
  int c0 = cb * 64;
  int lr = lane & 15, lk = (lane >> 4) * 8;
  f32x4 acc0[4] = {}, acc1[4] = {};
  for (int k0 = 0; k0 < 256; k0 += 32) {
    bf16x8 a0 = *(const bf16x8*)&aggb[(size_t)(r0 + lr) * 256 + k0 + lk];
    bf16x8 a1 = *(const bf16x8*)&aggb[(size_t)(r0 + 16 + lr) * 256 + k0 + lk];
    bf16x8 b0 = *(const bf16x8*)&WoutT[(size_t)(c0 + lr) * 256 + k0 + lk];
    bf16x8 b1 = *(const bf16x8*)&WoutT[(size_t)(c0 + 16 + lr) * 256 + k0 + lk];
    bf16x8 b2 = *(const bf16x8*)&WoutT[(size_t)(c0 + 32 + lr) * 256 + k0 + lk];
    bf16x8 b3 = *(const bf16x8*)&WoutT[(size_t)(c0 + 48 + lr) * 256 + k0 + lk];
    acc0[0] = __builtin_amdgcn_mfma_f32_16x16x32_bf16(a0, b0, acc0[0], 0, 0, 0);
    acc0[1] = __builtin_amdgcn_mfma_f32_16x16x32_bf16(a0, b1, acc0[1], 0, 0, 0);
    acc0[2] = __builtin_amdgcn_mfma_f32_16x16x32_bf16(a0, b2, acc0[2], 0, 0, 0);
    acc0[3] = __builtin_amdgcn_mfma_f32_16x16x32_bf16(a0, b3, acc0[3], 0, 0, 0);
    acc1[0] = __builtin_amdgcn_mfma_f32_16x16x32_bf16(a1, b0, acc1[0], 0, 0, 0);
    acc1[1] = __builtin_amdgcn_mfma_f32_16x16x32_bf16(a1, b1, acc1[1], 0, 0, 0);
    acc1[2] = __builtin_amdgcn_mfma_f32_16x16x32_bf16(a1, b2, acc1[2], 0, 0, 0);
    acc1[3] = __builtin_amdgcn_mfma_f32_16x16x32_bf16(a1, b3, acc1[3], 0, 0, 0);
  }
  int rbase = r0 + (lane >> 4) * 4;
  float degA[4], degB[4];
  #pragma unroll
  for (int r = 0; r < 4; ++r) {
    degA[r] = (float)cnt[rbase + r];
    degB[r] = (float)cnt[rbase + 16 + r];
  }
  #pragma unroll
  for (int cc = 0; cc < 4; ++cc) {
    int colC = c0 + cc*16 + lr;
    float bC = b_out[colC];
    float sC = 0.f, qC = 0.f;
    #pragma unroll
    for (int r = 0; r < 4; ++r) {
      int rowA = rbase + r, rowB = rbase + 16 + r;
      float v0 = acc0[cc][r] + x[(size_t)rowA * 256 + colC] + degA[r] * bC;
      float v1 = acc1[cc][r] + x[(size_t)rowB * 256 + colC] + degB[r] * bC;
      out[(size_t)rowA * 256 + colC] = v0;
      out[(size_t)rowB * 256 + colC] = v1;
      sC += v0 + v1; qC += v0*v0 + v1*v1;
    }
    #pragma unroll
    for (int msk = 16; msk <= 32; msk <<= 1) {
      sC += __shfl_xor(sC, msk); qC += __shfl_xor(qC, msk);
    }
    if (lane < 16) {
      atomicAdd(&bnsum[colC], sC); atomicAdd(&bnsq[colC], qC);
    }
  }
}

// ---------------------------------------------------------------------------
__global__ __launch_bounds__(256) void bnapply_k(float* __restrict__ out,
                                                 const float* __restrict__ bnsum,
                                                 const float* __restrict__ bnsq,
                                                 const float* __restrict__ gamma,
                                                 const float* __restrict__ beta) {
  int t = threadIdx.x;
  int c4 = t & 63;
  int r = blockIdx.x * 4 + (t >> 6);
  float4 s4 = ((const float4*)bnsum)[c4];
  float4 q4 = ((const float4*)bnsq)[c4];
  float4 g4 = ((const float4*)gamma)[c4];
  float4 b4 = ((const float4*)beta)[c4];
  float4 v = ((const float4*)out)[(size_t)r * 64 + c4];
  #pragma unroll
  for (int j = 0; j < 4; ++j) {
    float mu = (&s4.x)[j] * (1.f / 8192.f);
    float var = (&q4.x)[j] * (1.f / 8192.f) - mu*mu;
    float inv = rsqrtf(var + 1e-5f);
    (&v.x)[j] = ((&v.x)[j] - mu) * inv * (&g4.x)[j] + (&b4.x)[j];
  }
  ((float4*)out)[(size_t)r * 64 + c4] = v;
}

// ---------------------------------------------------------------------------
extern "C" void kernel_launch(void* const* d_in, const int* in_sizes, int n_in,
                              void* d_out, int out_size, void* d_ws, size_t ws_size,
                              hipStream_t stream) {
  (void)in_sizes; (void)n_in; (void)out_size; (void)ws_size;
  const float* x      = (const float*)d_in[0];
  const int*   ei     = (const int*)d_in[1];
  const float* eattr  = (const float*)d_in[2];
  const int*   qm     = (const int*)d_in[3];
  const float* W_kqv  = (const float*)d_in[5];
  const float* b_kqv  = (const float*)d_in[6];
  const float* W_edge = (const float*)d_in[7];
  const float* b_edge = (const float*)d_in[8];
  const float* W_att1 = (const float*)d_in[9];
  const float* b_att1 = (const float*)d_in[10];
  const float* W_att2 = (const float*)d_in[11];
  // b_att2 cancels in softmax
  const float* W_out  = (const float*)d_in[13];
  const float* b_out  = (const float*)d_in[14];
  const float* gamma  = (const float*)d_in[15];
  const float* beta   = (const float*)d_in[16];
  float* out = (float*)d_out;

  // workspace carve-up (~27 MB)
  char* w = (char*)d_ws;
  u16*    xb      = (u16*)w;     w += (size_t)N_NODES*256*2;
  u16*    BcatT   = (u16*)w;     w += (size_t)768*256*2;
  u16*    wa1t    = (u16*)w;     w += 1024*2;
  u16*    WoutT   = (u16*)w;     w += (size_t)256*256*2;
  u16*    nodeFb  = (u16*)w;     w += (size_t)N_NODES*768*2;
  float*  biascat = (float*)w;   w += 768*4;
  float*  beW     = (float*)w;   w += 256*4;
  u16*    aggb    = (u16*)w;     w += (size_t)N_NODES*256*2;
  int*    cnt     = (int*)w;     w += N_NODES*4;
  float*  bnsum   = (float*)w;   w += 256*4;
  float*  bnsq    = (float*)w;   w += 256*4;
  int*    csr     = (int*)w;     w += (size_t)N_NODES*DEGCAP*4;
  float*  lgd     = (float*)w;   w += (size_t)NSLOT*8*4;

  setup_k<<<2846, 256, 0, stream>>>(
      x, xb, W_kqv, b_kqv, W_att1, b_att1, W_edge, b_edge, W_out,
      BcatT, biascat, wa1t, WoutT, beW, (int4*)cnt);

  gemm_scatter_k<<<768 + (NSLOT + 255)/256, 256, 0, stream>>>(
      xb, BcatT, biascat, nodeFb, ei, qm, cnt, csr);

  logits_k<<<MAIN_BLKS + TAIL_BLKS, 128, 0, stream>>>(
      ei, eattr, nodeFb, wa1t, W_edge, b_edge, W_att2, beW, lgd);

  aggr_k<<<N_NODES/4, 256, 0, stream>>>(cnt, csr, lgd, nodeFb, aggb);

  gemmout_k<<<256, 256, 0, stream>>>(
      aggb, WoutT, x, cnt, b_out, out, bnsum, bnsq);

  bnapply_k<<<N_NODES/4, 256, 0, stream>>>(out, bnsum, bnsq, gamma, beta);
}